// Round 3
// baseline (276.123 us; speedup 1.0000x reference)
//
#include <hip/hip_runtime.h>
#include <math.h>

// x:    [B=8, C=4, H=256, W=256] f32
// filt: [B, C*25, H, W]          f32
// out:  [B, 1, H, W]             f32
// out[b,h,w] = tanh( sum_{c,p} x_pad[b,c,h+p/5-2, w+p%5-2] * filt[b,c*25+p,h,w] )
#define Hd 256
#define Wd 256
#define Cc 4
#define KK 5

typedef float v4f __attribute__((ext_vector_type(4)));

__global__ __launch_bounds__(256) void dynf_kernel(const float* __restrict__ x,
                                                   const float* __restrict__ filt,
                                                   float* __restrict__ out) {
    // Block = one (b,h) output row. Wave = one input channel c. Lane = 4-pixel group.
    const int bh   = blockIdx.x;            // [0, 2048)
    const int b    = bh >> 8;
    const int h    = bh & 255;
    const int c    = threadIdx.x >> 6;      // wave id = channel
    const int lane = threadIdx.x & 63;
    const int w0   = lane << 2;

    const size_t HW = (size_t)Hd * Wd;
    const float* xc = x + ((size_t)b * Cc + c) * HW;
    const float* fb = filt + ((size_t)(b * (Cc * KK * KK) + c * (KK * KK))) * HW
                      + (size_t)h * Wd + w0;

    float a0 = 0.f, a1 = 0.f, a2 = 0.f, a3 = 0.f;

    #pragma unroll
    for (int di = 0; di < KK; ++di) {
        const int hh = h + di - 2;
        if (hh >= 0 && hh < Hd) {                 // wave-uniform; padded rows contribute 0
            const float* xr = xc + (size_t)hh * Wd;
            // One aligned float4 per lane; halo comes from neighbor lanes via shuffle.
            v4f mid = *(const v4f*)(xr + w0);
            float lz = __shfl_up(mid.z, 1);       // x[w0-2] from lane-1
            float lw = __shfl_up(mid.w, 1);       // x[w0-1]
            float rx = __shfl_down(mid.x, 1);     // x[w0+4] from lane+1
            float ry = __shfl_down(mid.y, 1);     // x[w0+5]
            if (lane == 0)  { lz = 0.f; lw = 0.f; }   // zero-pad left edge
            if (lane == 63) { rx = 0.f; ry = 0.f; }   // zero-pad right edge
            float xrow[8] = {lz, lw, mid.x, mid.y, mid.z, mid.w, rx, ry};

            const float* fr = fb + (size_t)(di * KK) * HW;
            #pragma unroll
            for (int dj = 0; dj < KK; ++dj) {
                // nontemporal: filt has zero reuse — keep it out of x's cache space
                v4f f = __builtin_nontemporal_load((const v4f*)(fr + (size_t)dj * HW));
                a0 = fmaf(xrow[dj + 0], f.x, a0);
                a1 = fmaf(xrow[dj + 1], f.y, a1);
                a2 = fmaf(xrow[dj + 2], f.z, a2);
                a3 = fmaf(xrow[dj + 3], f.w, a3);
            }
        }
    }

    // Reduce the 4 channel-waves through LDS (b128, conflict-free).
    __shared__ v4f red[Cc][64];
    v4f acc = {a0, a1, a2, a3};
    red[c][lane] = acc;
    __syncthreads();

    if (c == 0) {
        v4f s = red[0][lane] + red[1][lane] + red[2][lane] + red[3][lane];
        v4f o;
        o.x = tanhf(s.x); o.y = tanhf(s.y); o.z = tanhf(s.z); o.w = tanhf(s.w);
        __builtin_nontemporal_store(o, (v4f*)(out + (size_t)b * HW + (size_t)h * Wd + w0));
    }
}

extern "C" void kernel_launch(void* const* d_in, const int* in_sizes, int n_in,
                              void* d_out, int out_size, void* d_ws, size_t ws_size,
                              hipStream_t stream) {
    const float* x    = (const float*)d_in[0];   // [8,4,256,256]
    const float* filt = (const float*)d_in[1];   // [8,100,256,256]
    float* out        = (float*)d_out;           // [8,1,256,256]

    const int grid  = 8 * 256;   // one block per (b,h) row
    const int block = 256;       // 4 waves = 4 channels
    dynf_kernel<<<grid, block, 0, stream>>>(x, filt, out);
}